// Round 1
// baseline (317.375 us; speedup 1.0000x reference)
//
#include <hip/hip_runtime.h>

#define BB 32
#define H 256
#define W 256
#define NC 25
#define KS 5
#define TILE 32
#define GT_T 40   // TILE + 2*4 halo (appear halo 2 + its own conv halo 2)
#define AP_T 36   // TILE + 2*2 halo

__global__ __launch_bounds__(256, 4)
void gtnet_fused(const float* __restrict__ im_input,
                 const float* __restrict__ m_kernel,
                 const int* __restrict__ gt,
                 float* __restrict__ out_pred,
                 float* __restrict__ out_mask,
                 float* __restrict__ out_app)
{
    __shared__ __align__(16) int   s_gt[GT_T][GT_T];      // gt tile + halo, -1 = OOB
    __shared__             float   s_wk[NC * NC + 7];     // 625 weights [cls][i*5+j]
    __shared__ __align__(16) float s_img[AP_T][AP_T][4];  // {im0*a, im1*a, im2*a, appear}

    const int tid = threadIdx.x;
    const int bx  = blockIdx.x;                 // 0 .. 2047
    const int tiles_per_row = W / TILE;         // 8
    const int tiles_per_img = (H / TILE) * tiles_per_row; // 64
    const int b  = bx / tiles_per_img;
    const int t  = bx % tiles_per_img;
    const int oh = (t / tiles_per_row) * TILE;
    const int ow = (t % tiles_per_row) * TILE;

    // ---- load weights ----
    for (int i = tid; i < NC * NC; i += 256) s_wk[i] = m_kernel[i];

    // ---- load gt tile with halo 4 ----
    const int* gtb = gt + b * (H * W);
    for (int i = tid; i < GT_T * GT_T; i += 256) {
        int y = i / GT_T, x = i % GT_T;
        int gy = oh - 4 + y, gx = ow - 4 + x;
        int v = -1;
        if (gy >= 0 && gy < H && gx >= 0 && gx < W) v = gtb[gy * W + gx];
        s_gt[y][x] = v;
    }
    __syncthreads();

    // ---- one-hot m_mask writes (fire early; drains while we compute) ----
    {
        float* mb = out_mask + (size_t)b * (NC * H * W);
        const int y  = tid >> 3;        // 0..31
        const int x4 = tid & 7;         // 0..7 -> 4-wide chunks
        const int4 g = *reinterpret_cast<const int4*>(&s_gt[y + 4][4 + 4 * x4]);
        #pragma unroll
        for (int c = 0; c < NC; ++c) {
            float4 v;
            v.x = (g.x == c) ? 1.f : 0.f;
            v.y = (g.y == c) ? 1.f : 0.f;
            v.z = (g.z == c) ? 1.f : 0.f;
            v.w = (g.w == c) ? 1.f : 0.f;
            *reinterpret_cast<float4*>(&mb[(c * H + oh + y) * W + ow + 4 * x4]) = v;
        }
    }

    // ---- appear + gated image staging on 36x36 halo region ----
    const float* imb = im_input + ((size_t)b * 6 + 3) * (H * W);  // last 3 channels
    for (int idx = tid; idx < AP_T * AP_T; idx += 256) {
        int p = idx / AP_T, q = idx % AP_T;
        float seg = 0.f;
        #pragma unroll
        for (int i = 0; i < KS; ++i) {
            #pragma unroll
            for (int j = 0; j < KS; ++j) {
                int cls = s_gt[p + i][q + j];
                seg += (cls >= 0) ? s_wk[cls * NC + i * KS + j] : 0.f;
            }
        }
        float dis = fmaxf(seg - 1.f, 0.f);
        float app = fmaxf(1.f - dis, 0.f);
        int gy = oh - 2 + p, gx = ow - 2 + q;
        float i0 = 0.f, i1 = 0.f, i2 = 0.f;
        if (gy >= 0 && gy < H && gx >= 0 && gx < W) {
            int o = gy * W + gx;
            i0 = imb[o] * app;
            i1 = imb[H * W + o] * app;
            i2 = imb[2 * H * W + o] * app;
        }
        float4 v; v.x = i0; v.y = i1; v.z = i2; v.w = app;
        *reinterpret_cast<float4*>(&s_img[p][q][0]) = v;
    }
    __syncthreads();

    // ---- out_app = 1 - appear (central 32x32) ----
    {
        float* ab = out_app + (size_t)b * (H * W);
        #pragma unroll
        for (int k = 0; k < 4; ++k) {
            int idx = k * 256 + tid;
            int y = idx >> 5, x = idx & 31;
            ab[(oh + y) * W + ow + x] = 1.f - s_img[y + 2][x + 2][3];
        }
    }

    // ---- pred: each thread computes a 2x2 output patch, 3 channels ----
    {
        const int py = (tid >> 4) << 1;   // 0..30 even
        const int px = (tid & 15) << 1;   // 0..30 even
        float2 acc[2][3];
        #pragma unroll
        for (int dy = 0; dy < 2; ++dy)
            #pragma unroll
            for (int ch = 0; ch < 3; ++ch) { acc[dy][ch].x = 0.f; acc[dy][ch].y = 0.f; }

        #pragma unroll
        for (int sy = 0; sy < 6; ++sy) {
            #pragma unroll
            for (int sx = 0; sx < 6; ++sx) {
                int cls = s_gt[py + 2 + sy][px + 2 + sx];
                int cw  = (cls >= 0) ? cls : 0;   // im4 is 0 at OOB, weight value irrelevant
                const float4 im4 = *reinterpret_cast<const float4*>(&s_img[py + sy][px + sx][0]);
                #pragma unroll
                for (int dy = 0; dy < 2; ++dy) {
                    const int i = sy - dy;
                    if (i < 0 || i >= KS) continue;
                    #pragma unroll
                    for (int dx = 0; dx < 2; ++dx) {
                        const int j = sx - dx;
                        if (j < 0 || j >= KS) continue;
                        float w = s_wk[cw * NC + i * KS + j];
                        if (dx == 0) {
                            acc[dy][0].x += im4.x * w;
                            acc[dy][1].x += im4.y * w;
                            acc[dy][2].x += im4.z * w;
                        } else {
                            acc[dy][0].y += im4.x * w;
                            acc[dy][1].y += im4.y * w;
                            acc[dy][2].y += im4.z * w;
                        }
                    }
                }
            }
        }
        float* pb = out_pred + (size_t)b * 3 * H * W;
        #pragma unroll
        for (int ch = 0; ch < 3; ++ch)
            #pragma unroll
            for (int dy = 0; dy < 2; ++dy)
                *reinterpret_cast<float2*>(&pb[(ch * H + oh + py + dy) * W + ow + px]) = acc[dy][ch];
    }
}

extern "C" void kernel_launch(void* const* d_in, const int* in_sizes, int n_in,
                              void* d_out, int out_size, void* d_ws, size_t ws_size,
                              hipStream_t stream) {
    const float* im_input = (const float*)d_in[0];   // [32, 6, 256, 256] f32
    const float* m_kernel = (const float*)d_in[1];   // [1, 25, 5, 5]    f32
    const int*   gt       = (const int*)d_in[2];     // [32, 1, 256, 256] i32

    float* out_pred = (float*)d_out;                              // [32,3,256,256]
    float* out_mask = out_pred + (size_t)BB * 3 * H * W;          // [32,25,256,256]
    float* out_app  = out_mask + (size_t)BB * NC * H * W;         // [32,1,256,256]

    const int blocks = BB * (H / TILE) * (W / TILE);  // 2048
    gtnet_fused<<<blocks, 256, 0, stream>>>(im_input, m_kernel, gt,
                                            out_pred, out_mask, out_app);
}